// Round 4
// baseline (842.485 us; speedup 1.0000x reference)
//
#include <hip/hip_runtime.h>
#include <stdint.h>

#define SEQ  20
#define H1   128
#define H2   256
#define NCLS 100000
#define GRID 206

#define AQ  __ATOMIC_ACQUIRE
#define RL  __ATOMIC_RELEASE
#define RX  __ATOMIC_RELAXED
#define AG  __HIP_MEMORY_SCOPE_AGENT

// Opaque touch: forces v's components into VGPRs and forbids rematerializing
// the load (round-2/3 showed the allocator re-loading loop-invariant weights
// every serial step at VGPR_Count=60 despite a 128-reg budget).
#define KEEPF4(v) asm volatile("" : "+v"((v).x), "+v"((v).y), "+v"((v).z), "+v"((v).w))

__device__ __forceinline__ float sigm(float x) { return 1.0f / (1.0f + __expf(-x)); }
__device__ __forceinline__ float tanhfast(float x) {
    float e = __expf(-2.0f * fabsf(x));
    float t = (1.0f - e) / (1.0f + e);
    return copysignf(t, x);
}

// One fused kernel, 206 blocks x 1024 threads, all co-resident (1 block/CU):
//   bid in {0,8,...,72}  (stride 8 -> same XCD if dispatch is round-robin):
//     role 0..1  : layer-1 LSTM fwd/bwd
//     role 2..9  : layer-2 LSTM, 8 shards x 32 cells
//   all other bids: output GEMV, 196 blocks, 2 threads per class (k-split),
//     prefetching Wlin into L3 while the LSTM pipeline runs.
// LDS is a single overlaid arena (62.6 KB) -- round 3 showed per-branch
// __shared__ arrays get SUMMED (91.6 KB) otherwise.
__global__ __launch_bounds__(1024) __attribute__((amdgpu_waves_per_eu(4, 4)))
void k_fused(
    const float* __restrict__ x,
    const float* __restrict__ h0f, const float* __restrict__ c0f,
    const float* __restrict__ h0b, const float* __restrict__ c0b,
    const float* __restrict__ WihF, const float* __restrict__ WhhF,
    const float* __restrict__ bihF, const float* __restrict__ bhhF,
    const float* __restrict__ WihB, const float* __restrict__ WhhB,
    const float* __restrict__ bihB, const float* __restrict__ bhhB,
    const float* __restrict__ Wihl, const float* __restrict__ Whhl,
    const float* __restrict__ bihl, const float* __restrict__ bhhl,
    const float* __restrict__ h0l,  const float* __restrict__ c0l,
    const float* __restrict__ Wlin, const float* __restrict__ blin,
    float* __restrict__ comb, float* __restrict__ fb,
    float* __restrict__ hg2, int* __restrict__ flags,
    float* __restrict__ out)
{
    __shared__ __align__(16) float smem[16032];   // 64128 B overlaid arena
    const int bid = blockIdx.x;
    const int tid = threadIdx.x;
    const bool is_lstm = (bid < 80) && ((bid & 7) == 0);

    if (is_lstm && (bid >> 3) < 2) {
        // ================= layer-1: one block per direction ===============
        const int dir = bid >> 3;
        const float* Wih = dir ? WihB : WihF;
        const float* Whh = dir ? WhhB : WhhF;
        const float* bih = dir ? bihB : bihF;
        const float* bhh = dir ? bhhB : bhhF;
        const float* h0  = dir ? h0b  : h0f;
        const float* c0  = dir ? c0b  : c0f;

        float* xs      = smem;                    // 2560
        float* hcur    = xs + 2560;               // 128
        float* biasL   = hcur + 128;              // 512
        float* gxs     = biasL + 512;             // 512*21 = 10752
        float* partial = gxs + 10752;             // 4*520 = 2080

        for (int i = tid; i < SEQ * H1; i += 1024) xs[i] = x[i];
        if (tid < 4 * H1) biasL[tid] = bih[tid] + bhh[tid];
        if (tid < H1) hcur[tid] = h0[tid];
        float cregA = 0.f, cregB = 0.f;
        if (tid < 64) { cregA = c0[tid]; cregB = c0[tid + 64]; }

        // ---- prologue: thread = (row pr, half ph); Wih slice in regs ----
        const int pr = tid >> 1, ph = tid & 1;
        {
            float4 wf[16];
            const float4* p = (const float4*)(Wih + pr * H1 + ph * 64);
#pragma unroll
            for (int j = 0; j < 16; ++j) { wf[j] = p[j]; KEEPF4(wf[j]); }
            __syncthreads();
            for (int t = 0; t < SEQ; ++t) {
                const int tx = dir ? (SEQ - 1 - t) : t;
                const float4* xp = (const float4*)(xs + tx * H1 + ph * 64);
                float a = 0.f;
#pragma unroll
                for (int j = 0; j < 16; ++j) {
                    float4 v = xp[j];
                    a += wf[j].x * v.x + wf[j].y * v.y + wf[j].z * v.z + wf[j].w * v.w;
                }
                a += __shfl_xor(a, 1);
                if (ph == 0) gxs[pr * 21 + t] = a + biasL[pr];
            }
        }

        // ---- recurrence weights -> registers (forced) ----
        const int cg = tid >> 8, r0 = (tid & 255) * 2;
        float4 wa[8], wb[8];
        {
            const float4* pa = (const float4*)(Whh + r0 * H1 + cg * 32);
            const float4* pb = (const float4*)(Whh + (r0 + 1) * H1 + cg * 32);
#pragma unroll
            for (int j = 0; j < 8; ++j) {
                wa[j] = pa[j]; KEEPF4(wa[j]);
                wb[j] = pb[j]; KEEPF4(wb[j]);
            }
        }
        __syncthreads();

        for (int t = 0; t < SEQ; ++t) {
            const float4* hp = (const float4*)(hcur + cg * 32);   // broadcast
            float a0 = 0.f, a1 = 0.f;
#pragma unroll
            for (int j = 0; j < 8; ++j) {
                float4 v = hp[j];
                a0 += wa[j].x * v.x + wa[j].y * v.y + wa[j].z * v.z + wa[j].w * v.w;
                a1 += wb[j].x * v.x + wb[j].y * v.y + wb[j].z * v.z + wb[j].w * v.w;
            }
            *(float2*)(partial + cg * 520 + r0) = make_float2(a0, a1);
            __syncthreads();
            if (tid < 64) {                       // wave 0: finish 2 cells each
                const int c = tid;
                float s0[4], s1[4];
#pragma unroll
                for (int g = 0; g < 4; ++g) {
                    float accA = gxs[(g * H1 + c) * 21 + t];
                    float accB = gxs[(g * H1 + c + 64) * 21 + t];
#pragma unroll
                    for (int q = 0; q < 4; ++q) {
                        accA += partial[q * 520 + g * H1 + c];
                        accB += partial[q * 520 + g * H1 + c + 64];
                    }
                    s0[g] = accA; s1[g] = accB;
                }
                float cnA = sigm(s0[1]) * cregA + sigm(s0[0]) * tanhfast(s0[2]);
                float cnB = sigm(s1[1]) * cregB + sigm(s1[0]) * tanhfast(s1[2]);
                cregA = cnA; cregB = cnB;
                float hA = sigm(s0[3]) * tanhfast(cnA);
                float hB = sigm(s1[3]) * tanhfast(cnB);
                hcur[c] = hA; hcur[c + 64] = hB;
                __hip_atomic_store(&comb[t * H2 + dir * H1 + c],      hA, RX, AG);
                __hip_atomic_store(&comb[t * H2 + dir * H1 + c + 64], hB, RX, AG);
                // release by lane 0 of the SAME wave that issued the data
                // stores: wave-level vmcnt drain orders all 64 lanes' stores.
                if (tid == 0)
                    __hip_atomic_store(&flags[dir * 32], t + 1, RL, AG);
            }
            __syncthreads();
        }
    } else if (is_lstm) {
        // ================= layer-2: 8 shards x 32 cells ===================
        const int s = (bid >> 3) - 2;
        float* ct    = smem;                      // 256
        float* hc2   = ct + 256;                  // 256
        float* bias2 = hc2 + 256;                 // 128
        float* part2 = bias2 + 128;               // 8*132 = 1056

        const int cg = tid >> 7;                  // 0..7, wave-uniform
        const int L  = tid & 127;                 // local gate row
        const int R  = (L >> 5) * H2 + s * 32 + (L & 31);

        float4 wih[8], whh[8];
        {
            const float4* pi = (const float4*)(Wihl + (size_t)R * H2 + cg * 32);
            const float4* pw = (const float4*)(Whhl + (size_t)R * H2 + cg * 32);
#pragma unroll
            for (int j = 0; j < 8; ++j) {
                wih[j] = pi[j]; KEEPF4(wih[j]);
                whh[j] = pw[j]; KEEPF4(whh[j]);
            }
        }
        if (tid < 128) bias2[tid] = bihl[R] + bhhl[R];
        if (tid < H2)  hc2[tid] = h0l[tid];
        float creg = (tid < 32) ? c0l[s * 32 + tid] : 0.0f;
        __syncthreads();

        for (int t = 0; t < SEQ; ++t) {
            if (tid < 64) {                       // wait + stage comb[t]
                while (__hip_atomic_load(&flags[0],  AQ, AG) <= t ||
                       __hip_atomic_load(&flags[32], AQ, AG) <= t)
                    __builtin_amdgcn_s_sleep(1);
#pragma unroll
                for (int j = 0; j < 4; ++j)
                    ct[tid * 4 + j] =
                        __hip_atomic_load(&comb[t * H2 + tid * 4 + j], RX, AG);
            }
            __syncthreads();
            {
                const float4* cp = (const float4*)(ct  + cg * 32);  // broadcast
                const float4* hp = (const float4*)(hc2 + cg * 32);  // broadcast
                float a = 0.f;
#pragma unroll
                for (int j = 0; j < 8; ++j) {
                    float4 cv = cp[j], hv = hp[j];
                    a += wih[j].x * cv.x + wih[j].y * cv.y
                       + wih[j].z * cv.z + wih[j].w * cv.w
                       + whh[j].x * hv.x + whh[j].y * hv.y
                       + whh[j].z * hv.z + whh[j].w * hv.w;
                }
                part2[cg * 132 + L] = a;
            }
            __syncthreads();
            if (tid < 32) {                       // finish own 32 cells
                float sg[4];
#pragma unroll
                for (int g = 0; g < 4; ++g) {
                    float acc = bias2[g * 32 + tid];
#pragma unroll
                    for (int q = 0; q < 8; ++q) acc += part2[q * 132 + g * 32 + tid];
                    sg[g] = acc;
                }
                float cn = sigm(sg[1]) * creg + sigm(sg[0]) * tanhfast(sg[2]);
                creg = cn;
                float hn = sigm(sg[3]) * tanhfast(cn);
                hc2[s * 32 + tid] = hn;
                __hip_atomic_store(&fb[t * H2 + s * 32 + tid], hn, RX, AG);
                __hip_atomic_store(&hg2[s * 32 + tid],         hn, RX, AG);
                if (tid == 0)
                    __hip_atomic_store(&flags[(2 + s) * 32], t + 1, RL, AG);
            } else if (tid >= 64 && tid < 288 && t + 1 < SEQ) {
                // pull the 224 remote h values (skip own shard)
                const int idx = (s * 32 + tid - 32) & 255;
                const int sh  = idx >> 5;
                while (__hip_atomic_load(&flags[(2 + sh) * 32], AQ, AG) <= t)
                    __builtin_amdgcn_s_sleep(1);
                hc2[idx] = __hip_atomic_load(&hg2[idx], RX, AG);
            }
            __syncthreads();
        }
    } else {
        // ================= output GEMV: 196 blocks, 2 threads/class =======
        const int g  = (bid < 80) ? (bid - (bid >> 3) - 1) : (bid - 10);
        const int n  = g * 512 + (tid >> 1);
        const int kh = tid & 1;                   // k-half: cols kh*128..+128
        float* fbs = smem;                        // [H2][SEQ] = 5120 floats

        // prefetch own half-row into L3 while the LSTM pipeline runs
        float keep = 0.f;
        if (n < NCLS) {
            const float* wp = Wlin + (size_t)n * H2 + kh * 128;
#pragma unroll
            for (int j = 0; j < 8; ++j) keep += wp[j * 16];   // 64-B line stride
        }
        asm volatile("" :: "v"(keep));

        if (tid < 8) {
            while (__hip_atomic_load(&flags[(2 + tid) * 32], AQ, AG) < SEQ)
                __builtin_amdgcn_s_sleep(4);
        }
        __syncthreads();
        if (tid < H2) {
            for (int t = 0; t < SEQ; ++t)
                fbs[tid * SEQ + t] = __hip_atomic_load(&fb[t * H2 + tid], RX, AG);
        }
        __syncthreads();
        if (n >= NCLS) return;

        float bv = blin[n];
        float acc[SEQ];
#pragma unroll
        for (int t = 0; t < SEQ; ++t) acc[t] = 0.f;

        const float* wp = Wlin + (size_t)n * H2 + kh * 128;
        for (int k = 0; k < 128; k += 4) {
            float4 wv = *(const float4*)(wp + k);
            const float* f0 = fbs + (kh * 128 + k) * SEQ;     // broadcast reads
#pragma unroll
            for (int t = 0; t < SEQ; t += 4) {
                float4 a0 = *(const float4*)(f0 + t);
                float4 a1 = *(const float4*)(f0 + SEQ + t);
                float4 a2 = *(const float4*)(f0 + 2 * SEQ + t);
                float4 a3 = *(const float4*)(f0 + 3 * SEQ + t);
                acc[t]     += wv.x * a0.x + wv.y * a1.x + wv.z * a2.x + wv.w * a3.x;
                acc[t + 1] += wv.x * a0.y + wv.y * a1.y + wv.z * a2.y + wv.w * a3.y;
                acc[t + 2] += wv.x * a0.z + wv.y * a1.z + wv.z * a2.z + wv.w * a3.z;
                acc[t + 3] += wv.x * a0.w + wv.y * a1.w + wv.z * a2.w + wv.w * a3.w;
            }
        }
#pragma unroll
        for (int t = 0; t < SEQ; ++t) acc[t] += __shfl_xor(acc[t], 1);
#pragma unroll
        for (int t = 0; t < 10; ++t) {
            int tt = kh * 10 + t;
            out[(size_t)tt * NCLS + n] = acc[tt] + bv;
        }
    }
}

// ---------------------------------------------------------------------------
extern "C" void kernel_launch(void* const* d_in, const int* in_sizes, int n_in,
                              void* d_out, int out_size, void* d_ws, size_t ws_size,
                              hipStream_t stream)
{
    const float* x    = (const float*)d_in[0];
    const float* h0f_ = (const float*)d_in[1];
    const float* c0f_ = (const float*)d_in[2];
    const float* h0b_ = (const float*)d_in[3];
    const float* c0b_ = (const float*)d_in[4];
    const float* h0l_ = (const float*)d_in[5];
    const float* c0l_ = (const float*)d_in[6];
    const float* WihF = (const float*)d_in[7];
    const float* WhhF = (const float*)d_in[8];
    const float* bihF = (const float*)d_in[9];
    const float* bhhF = (const float*)d_in[10];
    const float* WihB = (const float*)d_in[11];
    const float* WhhB = (const float*)d_in[12];
    const float* bihB = (const float*)d_in[13];
    const float* bhhB = (const float*)d_in[14];
    const float* Wihl = (const float*)d_in[15];
    const float* Whhl = (const float*)d_in[16];
    const float* bihl = (const float*)d_in[17];
    const float* bhhl = (const float*)d_in[18];
    const float* Wlin = (const float*)d_in[19];
    const float* blin = (const float*)d_in[20];

    char* ws = (char*)d_ws;
    int*   flags = (int*)ws;                     // 10 flags, 128-B apart (2048 B)
    float* hg2   = (float*)(ws + 2048);          // [256]
    float* comb  = (float*)(ws + 4096);          // [20][256]
    float* fb    = (float*)(ws + 24576);         // [20][256]

    hipMemsetAsync(flags, 0, 2048, stream);

    k_fused<<<GRID, 1024, 0, stream>>>(
        x, h0f_, c0f_, h0b_, c0b_,
        WihF, WhhF, bihF, bhhF,
        WihB, WhhB, bihB, bhhB,
        Wihl, Whhl, bihl, bhhl,
        h0l_, c0l_, Wlin, blin,
        comb, fb, hg2, flags, (float*)d_out);
}

// Round 5
// 372.611 us; speedup vs baseline: 2.2610x; 2.2610x over previous
//
#include <hip/hip_runtime.h>
#include <stdint.h>

#define SEQ  20
#define H1   128
#define H2   256
#define NCLS 100000

#define AQ  __ATOMIC_ACQUIRE
#define RL  __ATOMIC_RELEASE
#define RX  __ATOMIC_RELAXED
#define AG  __HIP_MEMORY_SCOPE_AGENT

// Opaque touch: forbids rematerializing the weight loads inside serial loops.
#define KEEPF4(v) asm volatile("" : "+v"((v).x), "+v"((v).y), "+v"((v).z), "+v"((v).w))

__device__ __forceinline__ float sigm(float x) { return 1.0f / (1.0f + __expf(-x)); }
__device__ __forceinline__ float tanhfast(float x) {
    float e = __expf(-2.0f * fabsf(x));
    float t = (1.0f - e) / (1.0f + e);
    return copysignf(t, x);
}

// ---------------------------------------------------------------------------
// LSTM pipeline kernel. Grid 80 x 1024, but only bids with (bid&7)==0 are
// active (10 blocks) -> by the blockIdx%8 XCD round-robin heuristic they
// cluster on one XCD, making the flag exchange L2-local if the heuristic
// holds (harmless if not). Roles: 0,1 = layer-1 fwd/bwd; 2..9 = layer-2
// shards of 32 cells. NO other pollers exist (round-3/4 showed embedded
// GEMV spin-pollers create a coherence storm that dominates runtime).
// hg2 is parity-double-buffered: publisher of step t writes slot t&1,
// consumers of step t read slot t&1 -- one-full-step safety window.
// ---------------------------------------------------------------------------
__global__ __launch_bounds__(1024, 1) void k_lstm(
    const float* __restrict__ x,
    const float* __restrict__ h0f, const float* __restrict__ c0f,
    const float* __restrict__ h0b, const float* __restrict__ c0b,
    const float* __restrict__ WihF, const float* __restrict__ WhhF,
    const float* __restrict__ bihF, const float* __restrict__ bhhF,
    const float* __restrict__ WihB, const float* __restrict__ WhhB,
    const float* __restrict__ bihB, const float* __restrict__ bhhB,
    const float* __restrict__ Wihl, const float* __restrict__ Whhl,
    const float* __restrict__ bihl, const float* __restrict__ bhhl,
    const float* __restrict__ h0l,  const float* __restrict__ c0l,
    float* __restrict__ comb,      // [SEQ][H2]
    float* __restrict__ fb,        // [SEQ][H2]
    float* __restrict__ hg2,       // [2][H2] parity slots
    int* __restrict__ flags)       // 128-B-strided: [0]=l1f [1]=l1b [2+s]=l2 shard
{
    __shared__ __align__(16) float smem[16032];   // 64128 B overlaid arena
    const int bid = blockIdx.x;
    if (bid & 7) return;                          // inactive filler block
    const int role = bid >> 3;                    // 0..9
    const int tid  = threadIdx.x;

    if (role < 2) {
        // ================= layer-1: one block per direction ===============
        const int dir = role;
        const float* Wih = dir ? WihB : WihF;
        const float* Whh = dir ? WhhB : WhhF;
        const float* bih = dir ? bihB : bihF;
        const float* bhh = dir ? bhhB : bhhF;
        const float* h0  = dir ? h0b  : h0f;
        const float* c0  = dir ? c0b  : c0f;

        float* xs      = smem;                    // 2560
        float* hcur    = xs + 2560;               // 128
        float* biasL   = hcur + 128;              // 512
        float* gxs     = biasL + 512;             // 512*21 = 10752
        float* partial = gxs + 10752;             // 4*520 = 2080

        for (int i = tid; i < SEQ * H1; i += 1024) xs[i] = x[i];
        if (tid < 4 * H1) biasL[tid] = bih[tid] + bhh[tid];
        if (tid < H1) hcur[tid] = h0[tid];
        float cregA = 0.f, cregB = 0.f;
        if (tid < 64) { cregA = c0[tid]; cregB = c0[tid + 64]; }

        // ---- prologue: thread = (row pr, half ph); Wih slice in regs ----
        const int pr = tid >> 1, ph = tid & 1;
        {
            float4 wf[16];
            const float4* p = (const float4*)(Wih + pr * H1 + ph * 64);
#pragma unroll
            for (int j = 0; j < 16; ++j) { wf[j] = p[j]; KEEPF4(wf[j]); }
            __syncthreads();
            for (int t = 0; t < SEQ; ++t) {
                const int tx = dir ? (SEQ - 1 - t) : t;
                const float4* xp = (const float4*)(xs + tx * H1 + ph * 64);
                float a = 0.f;
#pragma unroll
                for (int j = 0; j < 16; ++j) {
                    float4 v = xp[j];
                    a += wf[j].x * v.x + wf[j].y * v.y + wf[j].z * v.z + wf[j].w * v.w;
                }
                a += __shfl_xor(a, 1);
                if (ph == 0) gxs[pr * 21 + t] = a + biasL[pr];
            }
        }

        // ---- recurrence weights -> registers ----
        const int cg = tid >> 8, r0 = (tid & 255) * 2;
        float4 wa[8], wb[8];
        {
            const float4* pa = (const float4*)(Whh + r0 * H1 + cg * 32);
            const float4* pb = (const float4*)(Whh + (r0 + 1) * H1 + cg * 32);
#pragma unroll
            for (int j = 0; j < 8; ++j) {
                wa[j] = pa[j]; KEEPF4(wa[j]);
                wb[j] = pb[j]; KEEPF4(wb[j]);
            }
        }
        __syncthreads();

        for (int t = 0; t < SEQ; ++t) {
            const float4* hp = (const float4*)(hcur + cg * 32);   // broadcast
            float a0 = 0.f, a1 = 0.f;
#pragma unroll
            for (int j = 0; j < 8; ++j) {
                float4 v = hp[j];
                a0 += wa[j].x * v.x + wa[j].y * v.y + wa[j].z * v.z + wa[j].w * v.w;
                a1 += wb[j].x * v.x + wb[j].y * v.y + wb[j].z * v.z + wb[j].w * v.w;
            }
            *(float2*)(partial + cg * 520 + r0) = make_float2(a0, a1);
            __syncthreads();
            if (tid < 64) {                       // finish 2 cells each
                const int c = tid;
                float s0[4], s1[4];
#pragma unroll
                for (int g = 0; g < 4; ++g) {
                    float accA = gxs[(g * H1 + c) * 21 + t];
                    float accB = gxs[(g * H1 + c + 64) * 21 + t];
#pragma unroll
                    for (int q = 0; q < 4; ++q) {
                        accA += partial[q * 520 + g * H1 + c];
                        accB += partial[q * 520 + g * H1 + c + 64];
                    }
                    s0[g] = accA; s1[g] = accB;
                }
                float cnA = sigm(s0[1]) * cregA + sigm(s0[0]) * tanhfast(s0[2]);
                float cnB = sigm(s1[1]) * cregB + sigm(s1[0]) * tanhfast(s1[2]);
                cregA = cnA; cregB = cnB;
                float hA = sigm(s0[3]) * tanhfast(cnA);
                float hB = sigm(s1[3]) * tanhfast(cnB);
                hcur[c] = hA; hcur[c + 64] = hB;
                __hip_atomic_store(&comb[t * H2 + dir * H1 + c],      hA, RX, AG);
                __hip_atomic_store(&comb[t * H2 + dir * H1 + c + 64], hB, RX, AG);
                // release from the same wave that issued the data stores
                if (tid == 0)
                    __hip_atomic_store(&flags[dir * 32], t + 1, RL, AG);
            }
            __syncthreads();
        }
    } else {
        // ================= layer-2: 8 shards x 32 cells ===================
        const int s = role - 2;
        float* ct    = smem;                      // 256
        float* hc2   = ct + 256;                  // 256
        float* bias2 = hc2 + 256;                 // 128
        float* part2 = bias2 + 128;               // 8*132 = 1056

        const int cg = tid >> 7;                  // 0..7, wave-uniform
        const int L  = tid & 127;                 // local gate row
        const int R  = (L >> 5) * H2 + s * 32 + (L & 31);

        float4 wih[8], whh[8];
        {
            const float4* pi = (const float4*)(Wihl + (size_t)R * H2 + cg * 32);
            const float4* pw = (const float4*)(Whhl + (size_t)R * H2 + cg * 32);
#pragma unroll
            for (int j = 0; j < 8; ++j) {
                wih[j] = pi[j]; KEEPF4(wih[j]);
                whh[j] = pw[j]; KEEPF4(whh[j]);
            }
        }
        if (tid < 128) bias2[tid] = bihl[R] + bhhl[R];
        if (tid < H2)  hc2[tid] = h0l[tid];
        float creg = (tid < 32) ? c0l[s * 32 + tid] : 0.0f;

        // stage ct for t=0 (wave 8; lane<32 -> fwd half/flag0, else bwd/flag1)
        if (tid >= 512 && tid < 576) {
            const int l = tid - 512;
            const int f = (l < 32) ? 0 : 32;
            while (__hip_atomic_load(&flags[f], AQ, AG) < 1)
                __builtin_amdgcn_s_sleep(1);
#pragma unroll
            for (int j = 0; j < 4; ++j)
                ct[l * 4 + j] = __hip_atomic_load(&comb[l * 4 + j], RX, AG);
        }
        __syncthreads();

        for (int t = 0; t < SEQ; ++t) {
            // ---- (A) dot: all threads, wih·ct + whh·h fused ----
            {
                const float4* cp = (const float4*)(ct  + cg * 32);  // broadcast
                const float4* hp = (const float4*)(hc2 + cg * 32);  // broadcast
                float a = 0.f;
#pragma unroll
                for (int j = 0; j < 8; ++j) {
                    float4 cv = cp[j], hv = hp[j];
                    a += wih[j].x * cv.x + wih[j].y * cv.y
                       + wih[j].z * cv.z + wih[j].w * cv.w
                       + whh[j].x * hv.x + whh[j].y * hv.y
                       + whh[j].z * hv.z + whh[j].w * hv.w;
                }
                part2[cg * 132 + L] = a;
            }
            __syncthreads();
            // ---- (B) finish / publish / pull, role-split by wave ----
            if (tid < 32) {
                float sg[4];
#pragma unroll
                for (int g = 0; g < 4; ++g) {
                    float acc = bias2[g * 32 + tid];
#pragma unroll
                    for (int q = 0; q < 8; ++q)
                        acc += part2[q * 132 + g * 32 + tid];
                    sg[g] = acc;
                }
                float cn = sigm(sg[1]) * creg + sigm(sg[0]) * tanhfast(sg[2]);
                creg = cn;
                float hn = sigm(sg[3]) * tanhfast(cn);
                hc2[s * 32 + tid] = hn;
                __hip_atomic_store(&fb[t * H2 + s * 32 + tid], hn, RX, AG);
                __hip_atomic_store(&hg2[(t & 1) * H2 + s * 32 + tid], hn, RX, AG);
                if (tid == 0)
                    __hip_atomic_store(&flags[(2 + s) * 32], t + 1, RL, AG);
            } else if (tid >= 64 && tid < 128 && t + 1 < SEQ) {
                // wave 1: pull remote h (8 lanes per shard, skip own)
                const int l  = tid - 64;
                const int sh = l >> 3;
                if (sh != s) {
                    while (__hip_atomic_load(&flags[(2 + sh) * 32], AQ, AG) < t + 1)
                        __builtin_amdgcn_s_sleep(1);
                    const int base = sh * 32 + (l & 7) * 4;
#pragma unroll
                    for (int j = 0; j < 4; ++j)
                        hc2[base + j] =
                            __hip_atomic_load(&hg2[(t & 1) * H2 + base + j], RX, AG);
                }
            } else if (tid >= 512 && tid < 576 && t + 1 < SEQ) {
                // wave 8: stage ct for t+1
                const int l = tid - 512;
                const int f = (l < 32) ? 0 : 32;
                while (__hip_atomic_load(&flags[f], AQ, AG) < t + 2)
                    __builtin_amdgcn_s_sleep(1);
#pragma unroll
                for (int j = 0; j < 4; ++j)
                    ct[l * 4 + j] =
                        __hip_atomic_load(&comb[(t + 1) * H2 + l * 4 + j], RX, AG);
            }
            __syncthreads();
        }
    }
}

// ---------------------------------------------------------------------------
// Output linear (round-0 proven version, untouched). Thread = one class.
// ---------------------------------------------------------------------------
__global__ __launch_bounds__(256, 4) void k_out_v(
    const float* __restrict__ Wlin, const float* __restrict__ blin,
    const float* __restrict__ fb, float* __restrict__ out)
{
    __shared__ float fbs[H2][SEQ];
    const int tid = threadIdx.x;
    for (int t = 0; t < SEQ; ++t) fbs[tid][t] = fb[t * H2 + tid];
    __syncthreads();

    int n = blockIdx.x * 256 + tid;
    if (n >= NCLS) return;
    float acc[SEQ];
    float bv = blin[n];
#pragma unroll
    for (int t = 0; t < SEQ; ++t) acc[t] = bv;

    const float* wp = Wlin + (size_t)n * H2;
    for (int k = 0; k < H2; k += 4) {
        float4 wv = *(const float4*)(wp + k);
#pragma unroll
        for (int t = 0; t < SEQ; t += 4) {
            float4 f0 = *(const float4*)(&fbs[k][t]);
            float4 f1 = *(const float4*)(&fbs[k + 1][t]);
            float4 f2 = *(const float4*)(&fbs[k + 2][t]);
            float4 f3 = *(const float4*)(&fbs[k + 3][t]);
            acc[t]     += wv.x * f0.x + wv.y * f1.x + wv.z * f2.x + wv.w * f3.x;
            acc[t + 1] += wv.x * f0.y + wv.y * f1.y + wv.z * f2.y + wv.w * f3.y;
            acc[t + 2] += wv.x * f0.z + wv.y * f1.z + wv.z * f2.z + wv.w * f3.z;
            acc[t + 3] += wv.x * f0.w + wv.y * f1.w + wv.z * f2.w + wv.w * f3.w;
        }
    }
#pragma unroll
    for (int t = 0; t < SEQ; ++t)
        out[(size_t)t * NCLS + n] = acc[t];
}

// ---------------------------------------------------------------------------
extern "C" void kernel_launch(void* const* d_in, const int* in_sizes, int n_in,
                              void* d_out, int out_size, void* d_ws, size_t ws_size,
                              hipStream_t stream)
{
    const float* x    = (const float*)d_in[0];
    const float* h0f_ = (const float*)d_in[1];
    const float* c0f_ = (const float*)d_in[2];
    const float* h0b_ = (const float*)d_in[3];
    const float* c0b_ = (const float*)d_in[4];
    const float* h0l_ = (const float*)d_in[5];
    const float* c0l_ = (const float*)d_in[6];
    const float* WihF = (const float*)d_in[7];
    const float* WhhF = (const float*)d_in[8];
    const float* bihF = (const float*)d_in[9];
    const float* bhhF = (const float*)d_in[10];
    const float* WihB = (const float*)d_in[11];
    const float* WhhB = (const float*)d_in[12];
    const float* bihB = (const float*)d_in[13];
    const float* bhhB = (const float*)d_in[14];
    const float* Wihl = (const float*)d_in[15];
    const float* Whhl = (const float*)d_in[16];
    const float* bihl = (const float*)d_in[17];
    const float* bhhl = (const float*)d_in[18];
    const float* Wlin = (const float*)d_in[19];
    const float* blin = (const float*)d_in[20];

    char* ws = (char*)d_ws;
    int*   flags = (int*)ws;                     // 10 flags, 128-B apart (2048 B)
    float* hg2   = (float*)(ws + 2048);          // [2][256] parity slots
    float* comb  = (float*)(ws + 4096);          // [20][256]
    float* fb    = (float*)(ws + 24576);         // [20][256]

    hipMemsetAsync(flags, 0, 2048, stream);

    k_lstm<<<80, 1024, 0, stream>>>(
        x, h0f_, c0f_, h0b_, c0b_,
        WihF, WhhF, bihF, bhhF,
        WihB, WhhB, bihB, bhhB,
        Wihl, Whhl, bihl, bhhl,
        h0l_, c0l_,
        comb, fb, hg2, flags);
    k_out_v<<<391, 256, 0, stream>>>(Wlin, blin, fb, (float*)d_out);
}